// Round 15
// baseline (800.037 us; speedup 1.0000x reference)
//
#include <hip/hip_runtime.h>
#include <stdint.h>

#define B_   8
#define T_   2048
#define C_   1024
#define H_   2048
#define E_   8
#define CAP_ 640
#define RPE_ (B_*CAP_)   // 5120 rows per expert (max)
#define BT_  (B_*T_)     // 16384 tokens

typedef __attribute__((ext_vector_type(8))) short bf16x8;
typedef __attribute__((ext_vector_type(4))) float f32x4;

static __device__ __forceinline__ unsigned short f2bf(float f){
  union { float f; uint32_t u; } a; a.f = f;
  uint32_t u = a.u;
  uint32_t r = (u + 0x7FFFu + ((u >> 16) & 1u)) >> 16;   // RTNE
  return (unsigned short)r;
}

#define GLD16(gp, lp) __builtin_amdgcn_global_load_lds( \
    (__attribute__((address_space(1))) void*)(gp), \
    (__attribute__((address_space(3))) void*)(lp), 16, 0, 0)

#define VMW(N) asm volatile("s_waitcnt vmcnt(" #N ")" ::: "memory")
#define FENCE  asm volatile("" ::: "memory")
#define BARS   do { FENCE; __builtin_amdgcn_s_barrier(); __builtin_amdgcn_sched_barrier(0); } while(0)
#define BARE   do { __builtin_amdgcn_sched_barrier(0); FENCE; __builtin_amdgcn_s_barrier(); FENCE; } while(0)

// register-resident fragment loads (gemm1, 256-wide B in two halves)
#define LDA(H) do { \
  _Pragma("unroll") for (int ks_=0; ks_<2; ++ks_) \
  _Pragma("unroll") for (int f_=0; f_<4; ++f_) \
    pa[ks_][f_] = *(const bf16x8*)(bufc + (H)*16384u + aRow + (unsigned)f_*2048u + cc[ks_]); \
} while(0)
#define LDB(PB, H) do { \
  _Pragma("unroll") for (int ks_=0; ks_<2; ++ks_) \
  _Pragma("unroll") for (int n_=0; n_<2; ++n_) \
    PB[ks_][n_] = *(const bf16x8*)(bufc + 32768u + (H)*16384u + bRow + (unsigned)n_*2048u + cc[ks_]); \
} while(0)
#define MM16(Q, PB) do { \
  __builtin_amdgcn_s_setprio(1); \
  _Pragma("unroll") for (int ks_=0; ks_<2; ++ks_) \
  _Pragma("unroll") for (int f_=0; f_<4; ++f_) \
  _Pragma("unroll") for (int n_=0; n_<2; ++n_) \
    acc[Q][f_][n_] = __builtin_amdgcn_mfma_f32_16x16x32_bf16(pa[ks_][f_], PB[ks_][n_], acc[Q][f_][n_], 0,0,0); \
  __builtin_amdgcn_s_setprio(0); \
} while(0)

// gemm1 staging (double buffer, 64 KB stride)
#define STG_A(H, T1) do { \
  unsigned kb_ = (unsigned)(T1)*128u; \
  unsigned db_ = ((unsigned)(T1)&1u)*65536u + (H)*16384u; \
  GLD16(pA##H##0 + kb_, lds + db_ + d0); \
  GLD16(pA##H##1 + kb_, lds + db_ + 8192u + d0); \
} while(0)
#define STG_B(H, T1) do { \
  unsigned kb_ = (unsigned)(T1)*128u; \
  unsigned db_ = ((unsigned)(T1)&1u)*65536u + 32768u + (H)*16384u; \
  GLD16(pB##H##0 + kb_, lds + db_ + d0); \
  GLD16(pB##H##1 + kb_, lds + db_ + 8192u + d0); \
} while(0)

// gemm2 staging (double buffer, 48 KB stride: A0 16K | A1 16K | B 16K)
#define SG2A(H, T1) do { \
  unsigned kb_ = (unsigned)(T1)*128u; \
  unsigned db_ = ((unsigned)(T1)&1u)*49152u + (H)*16384u; \
  GLD16(pA##H##0 + kb_, lds + db_ + d0); \
  GLD16(pA##H##1 + kb_, lds + db_ + 8192u + d0); \
} while(0)
#define SG2B(T1) do { \
  unsigned kb_ = (unsigned)(T1)*128u; \
  unsigned db_ = ((unsigned)(T1)&1u)*49152u + 32768u; \
  GLD16(pB00 + kb_, lds + db_ + d0); \
  GLD16(pB01 + kb_, lds + db_ + 8192u + d0); \
} while(0)
#define LDB2 do { \
  _Pragma("unroll") for (int ks_=0; ks_<2; ++ks_) \
  _Pragma("unroll") for (int n_=0; n_<2; ++n_) \
    pb[ks_][n_] = *(const bf16x8*)(bufc + 32768u + bRow + (unsigned)n_*2048u + cc[ks_]); \
} while(0)

// ---------------- router: logits (fp64 acc), softmax, top-2, x->bf16 ----------------
__global__ __launch_bounds__(256) void router_kernel(
    const float* __restrict__ x, const float* __restrict__ wr,
    unsigned short* __restrict__ xbf, float* __restrict__ probs2, int* __restrict__ idx2)
{
  int bt = blockIdx.x;
  int tid = threadIdx.x;
  const float4 v = ((const float4*)(x + (size_t)bt*C_))[tid];
  ushort4 u;
  u.x = f2bf(v.x); u.y = f2bf(v.y); u.z = f2bf(v.z); u.w = f2bf(v.w);
  ((ushort4*)(xbf + (size_t)bt*C_))[tid] = u;

  double p[8];
  #pragma unroll
  for (int e=0;e<8;e++) p[e]=0.0;
  const float xv[4] = {v.x, v.y, v.z, v.w};
  #pragma unroll
  for (int j=0;j<4;j++){
    int c = tid*4+j;
    const float* wrow = wr + c*8;
    #pragma unroll
    for (int e=0;e<8;e++) p[e] += (double)xv[j] * (double)wrow[e];
  }
  __shared__ double red[8][256];
  #pragma unroll
  for (int e=0;e<8;e++) red[e][tid] = p[e];
  __syncthreads();
  for (int s=128; s>0; s>>=1){
    if (tid < s){
      #pragma unroll
      for (int e=0;e<8;e++) red[e][tid] += red[e][tid+s];
    }
    __syncthreads();
  }
  if (tid==0){
    double lg[8];
    #pragma unroll
    for (int e=0;e<8;e++) lg[e]=red[e][0];
    double mx = lg[0];
    #pragma unroll
    for (int e=1;e<8;e++) if (lg[e]>mx) mx=lg[e];
    double s=0.0, ex[8];
    #pragma unroll
    for (int e=0;e<8;e++){ ex[e]=exp(lg[e]-mx); s+=ex[e]; }
    int i1=0; double b1=ex[0];
    #pragma unroll
    for (int e=1;e<8;e++) if (ex[e]>b1){ b1=ex[e]; i1=e; }
    int i2=-1; double b2=-1.0;
    #pragma unroll
    for (int e=0;e<8;e++) if (e!=i1 && ex[e]>b2){ b2=ex[e]; i2=e; }
    probs2[bt*2+0] = (float)(b1/s);
    probs2[bt*2+1] = (float)(b2/s);
    idx2[bt*2+0] = i1;
    idx2[bt*2+1] = i2;
  }
}

// ---- fused fc+gate transpose: fp32[z][C][H] x2 -> bf16[z][4096][1024] interleaved ----
__global__ __launch_bounds__(256) void transp_fcg_kernel(
    const float* __restrict__ fc, const float* __restrict__ gate,
    unsigned short* __restrict__ dst)
{
  __shared__ float t[32][33];
  int e = blockIdx.z;
  int n0 = blockIdx.x*32, k0 = blockIdx.y*32;
  int tx = threadIdx.x & 31, ty = threadIdx.x >> 5;
  #pragma unroll
  for (int sel=0; sel<2; ++sel){
    const float* s = (sel ? gate : fc) + ((size_t)e*C_ + k0)*H_ + n0;
    #pragma unroll
    for (int i=0;i<32;i+=8) t[ty+i][tx] = s[(size_t)(ty+i)*H_ + tx];
    __syncthreads();
    #pragma unroll
    for (int i=0;i<32;i+=8){
      int jj = ty+i;
      int drow = n0*2 + ((jj & 16) << 1) + sel*16 + (jj & 15);
      dst[((size_t)e*4096 + drow)*1024 + k0 + tx] = f2bf(t[tx][jj]);
    }
    __syncthreads();
  }
}

// ---------------- weight transpose fp32[z][K][N] -> bf16[z][N][K] (w_c_proj) ----------------
__global__ __launch_bounds__(256) void transp_kernel(
    const float* __restrict__ src, unsigned short* __restrict__ dst, int K, int N)
{
  __shared__ float t[32][33];
  int e = blockIdx.z;
  int n0 = blockIdx.x*32, k0 = blockIdx.y*32;
  int tx = threadIdx.x & 31, ty = threadIdx.x >> 5;
  const float* s = src + ((size_t)e*K + k0)*N + n0;
  #pragma unroll
  for (int i=0;i<32;i+=8) t[ty+i][tx] = s[(size_t)(ty+i)*N + tx];
  __syncthreads();
  unsigned short* d = dst + ((size_t)e*N + n0)*K + k0;
  #pragma unroll
  for (int i=0;i<32;i+=8) d[(size_t)(ty+i)*K + tx] = f2bf(t[tx][ty+i]);
}

// ---------------- dispatch scan: exact k-major cumsum slot assignment ----------------
__global__ void scan_kernel(const int* __restrict__ idx2, int* __restrict__ pos, int* __restrict__ cnt)
{
  int b = blockIdx.x, lane = threadIdx.x;  // 64 threads
  unsigned long long below = (lane == 0) ? 0ull : (~0ull >> (64 - lane));
  int base = 0;
  for (int k=0;k<2;k++){
    for (int c0=0;c0<T_;c0+=64){
      int t = c0 + lane;
      int e = idx2[((b*T_ + t)<<1) + k];
      unsigned long long mym = 0; int addv = 0;
      #pragma unroll
      for (int ee=0; ee<8; ++ee){
        unsigned long long m = __ballot(e == ee);
        if (ee == e) mym = m;
        if (lane == ee) addv = __popcll(m);
      }
      int mybase = __shfl(base, e, 64);
      pos[((b*T_+t)<<1)+k] = mybase + __popcll(mym & below);
      base += addv;
    }
  }
  if (lane < 8) cnt[b*8 + lane] = (base < CAP_) ? base : CAP_;
}

__global__ void offsets_kernel(const int* __restrict__ cnt, int* __restrict__ off, int* __restrict__ Me)
{
  int e = threadIdx.x;
  if (e < 8){
    int s = 0;
    for (int b=0;b<8;b++){ off[e*8+b] = s; s += cnt[b*8+e]; }
    Me[e] = s;
  }
}

__global__ void fill_kernel(const int* __restrict__ idx2, const int* __restrict__ pos,
                            const int* __restrict__ off, const float* __restrict__ probs2,
                            int* __restrict__ token_src, float* __restrict__ row_prob)
{
  int a = blockIdx.x*256 + threadIdx.x;
  if (a >= BT_*2) return;
  int bt = a >> 1, k = a & 1;
  int b = bt >> 11;
  int e = idx2[bt*2+k];
  int p = pos[bt*2+k];
  if (p < CAP_){
    int r = e*RPE_ + off[e*8+b] + p;
    token_src[r] = bt;
    row_prob[r] = probs2[bt*2+k];
  }
}

// ---------------- GEMM1: 256x256x64, 8-phase, reg-resident halves; silu(g)*h ----------------
// 1-D grid, XCD-grouped: per-ez 320 blocks; nt = xcd + 8*(slot/20), mt = slot%20
__global__ __launch_bounds__(512, 2) void gemm1_kernel(
    const unsigned short* __restrict__ xbf,
    const unsigned short* __restrict__ wifcg,  // per-chunk base: [z][4096][1024]
    const int* __restrict__ token_src,
    const int* __restrict__ Me,
    unsigned short* __restrict__ act,          // chunk-local [z][RPE][H]
    int e0)
{
  const int lin = blockIdx.x;
  const int ez = lin / 320;
  const int r_ = lin % 320;
  const int xcd = r_ & 7, slot = r_ >> 3;          // slot 0..39
  const int nt = xcd + ((slot / 20) << 3);         // 0..15
  const int mt = slot % 20;                        // 0..19
  const int e = e0 + ez;
  const int M = Me[e];
  if (mt*256 >= M) return;

  __shared__ __align__(16) unsigned char lds[131072];

  const int tid = threadIdx.x;
  const int w = tid >> 6, l = tid & 63;
  const int wm = w >> 2, wn = w & 3;
  const int l15 = l & 15, g0 = l >> 4;
  const unsigned d0 = (unsigned)tid * 16u;

  const int srow0 = tid >> 3, c0 = tid & 7;
  const unsigned scb = (unsigned)((c0 ^ (srow0 & 7)) * 16);
  const unsigned char* gA = (const unsigned char*)xbf;
  const unsigned char* gB = (const unsigned char*)wifcg;
  const int abase = e*RPE_ + mt*256;
  const unsigned char* pA00 = gA + (size_t)token_src[abase +       srow0]*2048u + scb;
  const unsigned char* pA01 = gA + (size_t)token_src[abase +  64 + srow0]*2048u + scb;
  const unsigned char* pA10 = gA + (size_t)token_src[abase + 128 + srow0]*2048u + scb;
  const unsigned char* pA11 = gA + (size_t)token_src[abase + 192 + srow0]*2048u + scb;
  const size_t bbase = (size_t)(ez*4096 + nt*256 + srow0);
  const unsigned char* pB00 = gB + (bbase +   0)*2048u + scb;
  const unsigned char* pB01 = gB + (bbase +  64)*2048u + scb;
  const unsigned char* pB10 = gB + (bbase + 128)*2048u + scb;
  const unsigned char* pB11 = gB + (bbase + 192)*2048u + scb;

  const unsigned aRow = (unsigned)((wm*64 + l15) * 128);
  const unsigned bRow = (unsigned)((wn*32 + l15) * 128);
  unsigned cc[2];
  cc[0] = (unsigned)(((0*4 + g0) ^ (l15 & 7)) * 16);
  cc[1] = (unsigned)(((1*4 + g0) ^ (l15 & 7)) * 16);

  f32x4 acc[4][4][2];
  #pragma unroll
  for (int p=0;p<4;++p)
    #pragma unroll
    for (int f=0;f<4;++f)
      #pragma unroll
      for (int n=0;n<2;++n) acc[p][f][n] = (f32x4){0.f,0.f,0.f,0.f};

  bf16x8 pa[2][4], pb0[2][2], pb1[2][2];

  STG_A(0,0); STG_B(0,0); STG_B(1,0); STG_A(1,0);
  VMW(4);
  FENCE; __builtin_amdgcn_s_barrier(); FENCE;

  const int NT = 16;  // K=1024/64
  for (int t = 0; t < NT-1; ++t){
    const unsigned char* bufc = lds + (unsigned)(t&1)*65536u;
    LDA(0); LDB(pb0,0); STG_A(0,t+1); VMW(4); BARS; MM16(0,pb0); BARE;
    LDB(pb1,1);         STG_B(0,t+1); VMW(4); BARS; MM16(1,pb1); BARE;
    LDA(1);             STG_B(1,t+1);         BARS; MM16(2,pb0); BARE;
                        STG_A(1,t+1); VMW(4); BARS; MM16(3,pb1); BARE;
  }
  {
    const unsigned char* bufc = lds + (unsigned)((NT-1)&1)*65536u;
    LDA(0); LDB(pb0,0); VMW(2); BARS; MM16(0,pb0); BARE;
    LDB(pb1,1);         VMW(0); BARS; MM16(1,pb1); BARE;
    LDA(1);                     BARS; MM16(2,pb0); BARE;
                                BARS; MM16(3,pb1); BARE;
  }

  // epilogue: n=0 frag = h, n=1 frag = g (same logical cols); act = silu(g)*h
  const int r4 = (l >> 4) * 4;
  #pragma unroll
  for (int p=0;p<4;++p){
    const int ah = p>>1, bh = p&1;
    #pragma unroll
    for (int f=0;f<4;++f){
      const int grow = mt*256 + ah*128 + wm*64 + f*16 + r4;
      const int hcol = nt*128 + bh*64 + wn*16 + l15;
      #pragma unroll
      for (int r=0;r<4;++r){
        float h = acc[p][f][0][r];
        float gv = acc[p][f][1][r];
        float a = (gv / (1.f + __expf(-gv))) * h;
        act[((size_t)ez*RPE_ + grow + r)*(size_t)H_ + hcol] = f2bf(a);
      }
    }
  }
}

// ---- GEMM2: 256x128x64, 8-phase engine (2 phases/K-tile), dbuf 96KB; atomic scatter ----
// grid dim3(8, 20, ne): ~512 real blocks -> ~2 amortized CU rounds
__global__ __launch_bounds__(512, 2) void gemm2_kernel(
    const unsigned short* __restrict__ act,     // chunk-local [z][RPE][H]
    const unsigned short* __restrict__ wprojT,  // per-chunk base: [z][C][H]
    const int* __restrict__ token_src,
    const float* __restrict__ row_prob,
    const int* __restrict__ Me,
    float* __restrict__ y,
    int e0)
{
  const int ez = blockIdx.z, e = e0 + ez, mt = blockIdx.y, nt = blockIdx.x;  // nt 0..7
  const int M = Me[e];
  if (mt*256 >= M) return;

  __shared__ __align__(16) unsigned char lds[98304];  // 2 x (A0 16K | A1 16K | B 16K)

  const int tid = threadIdx.x;
  const int w = tid >> 6, l = tid & 63;
  const int wm = w >> 2, wn = w & 3;
  const int l15 = l & 15, g0 = l >> 4;
  const unsigned d0 = (unsigned)tid * 16u;

  const int srow0 = tid >> 3, c0 = tid & 7;
  const unsigned scb = (unsigned)((c0 ^ (srow0 & 7)) * 16);
  const unsigned char* gA = (const unsigned char*)act;
  const unsigned char* gB = (const unsigned char*)wprojT;
  const size_t abase = (size_t)(ez*RPE_ + mt*256 + srow0);
  const unsigned char* pA00 = gA + (abase +   0)*4096u + scb;
  const unsigned char* pA01 = gA + (abase +  64)*4096u + scb;
  const unsigned char* pA10 = gA + (abase + 128)*4096u + scb;
  const unsigned char* pA11 = gA + (abase + 192)*4096u + scb;
  const size_t bbase = (size_t)(ez*C_ + nt*128 + srow0);
  const unsigned char* pB00 = gB + (bbase +   0)*4096u + scb;
  const unsigned char* pB01 = gB + (bbase +  64)*4096u + scb;

  const unsigned aRow = (unsigned)((wm*64 + l15) * 128);
  const unsigned bRow = (unsigned)((wn*32 + l15) * 128);
  unsigned cc[2];
  cc[0] = (unsigned)(((0*4 + g0) ^ (l15 & 7)) * 16);
  cc[1] = (unsigned)(((1*4 + g0) ^ (l15 & 7)) * 16);

  f32x4 acc[2][4][2];
  #pragma unroll
  for (int p=0;p<2;++p)
    #pragma unroll
    for (int f=0;f<4;++f)
      #pragma unroll
      for (int n=0;n<2;++n) acc[p][f][n] = (f32x4){0.f,0.f,0.f,0.f};

  bf16x8 pa[2][4], pb[2][2];

  // prologue: A0(0),B(0),A1(0); confirm A0(0)+B(0)
  SG2A(0,0); SG2B(0); SG2A(1,0);
  VMW(2);
  FENCE; __builtin_amdgcn_s_barrier(); FENCE;

  const int NT = 32;  // K=2048/64
  for (int t = 0; t < NT-1; ++t){
    const unsigned char* bufc = lds + (unsigned)(t&1)*49152u;
    // ph0: reads A0(t),B(t); stage A0(t+1),B(t+1); VMW(4) confirms A1(t)
    LDA(0); LDB2; SG2A(0,t+1); SG2B(t+1); VMW(4); BARS; MM16(0,pb); BARE;
    // ph1: reads A1(t); stage A1(t+1); VMW(2) confirms A0(t+1),B(t+1)
    LDA(1);       SG2A(1,t+1);           VMW(2); BARS; MM16(1,pb); BARE;
  }
  {
    const unsigned char* bufc = lds + (unsigned)((NT-1)&1)*49152u;
    LDA(0); LDB2; VMW(0); BARS; MM16(0,pb); BARE;
    LDA(1);               BARS; MM16(1,pb); BARE;
  }

  // epilogue: scatter p * o into y (atomic, <=2 contributions per y element)
  const int r4 = (l >> 4) * 4;
  #pragma unroll
  for (int p=0;p<2;++p){   // p == AH
    #pragma unroll
    for (int f=0;f<4;++f){
      #pragma unroll
      for (int r=0;r<4;++r){
        const int rloc = mt*256 + p*128 + wm*64 + f*16 + r4 + r;
        if (rloc < M){
          const int bt = token_src[e*RPE_ + rloc];
          const float pp = row_prob[e*RPE_ + rloc];
          float* yrow = y + (size_t)bt*C_;
          const int colb = nt*128 + wn*32 + l15;
          atomicAdd(yrow + colb,      pp * acc[p][f][0][r]);
          atomicAdd(yrow + colb + 16, pp * acc[p][f][1][r]);
        }
      }
    }
  }
}

extern "C" void kernel_launch(void* const* d_in, const int* in_sizes, int n_in,
                              void* d_out, int out_size, void* d_ws, size_t ws_size,
                              hipStream_t stream)
{
  const float* x   = (const float*)d_in[0];
  const float* wr  = (const float*)d_in[1];
  const float* wfc = (const float*)d_in[2];
  const float* wg  = (const float*)d_in[3];
  const float* wpj = (const float*)d_in[4];
  float* y = (float*)d_out;

  unsigned char* ws = (unsigned char*)d_ws;
  const size_t szXBF  = (size_t)BT_*C_*2;            // 33,554,432
  const size_t szFCGc = (size_t)2*4096*1024*2;       // 16,777,216
  const size_t szWPc  = (size_t)2*C_*H_*2;           //  8,388,608
  const size_t szFCGa = (size_t)E_*4096*1024*2;      // 67,108,864
  const size_t szWPa  = (size_t)E_*C_*H_*2;          // 33,554,432
  const size_t szMISC = 3*131072 + 2*(size_t)E_*RPE_*4 + 1024;

  const size_t need_small = szXBF + szFCGc + szWPc + (size_t)2*RPE_*H_*2 + szMISC;
  const size_t need_big2  = szXBF + szFCGa + szWPa  + (size_t)2*RPE_*H_*2 + szMISC;
  const size_t need_big4  = szXBF + szFCGa + szWPa  + (size_t)4*RPE_*H_*2 + szMISC;
  if (ws_size < need_small) return;
  const bool big4 = (ws_size >= need_big4);
  const bool big  = big4 || (ws_size >= need_big2);
  const int  ne   = big4 ? 4 : 2;

  const size_t szFCG = big ? szFCGa : szFCGc;
  const size_t szWP  = big ? szWPa  : szWPc;
  const size_t szACT = (size_t)ne*RPE_*H_*2;

  size_t oXBF = 0;
  size_t oFCG = oXBF + szXBF;
  size_t oWP  = oFCG + szFCG;
  size_t oACT = oWP  + szWP;
  size_t oM   = oACT + szACT;

  unsigned short* xbf    = (unsigned short*)(ws + oXBF);
  unsigned short* wifcg  = (unsigned short*)(ws + oFCG);
  unsigned short* wprojT = (unsigned short*)(ws + oWP);
  unsigned short* actc   = (unsigned short*)(ws + oACT);

  float* probs2    = (float*)(ws + oM);
  int*   idx2      = (int*)(ws + oM + 1*131072);
  int*   pos       = (int*)(ws + oM + 2*131072);
  int*   token_src = (int*)(ws + oM + 3*131072);
  float* row_prob  = (float*)(ws + oM + 3*131072 + (size_t)E_*RPE_*4);
  int*   cnt       = (int*)(ws + oM + 3*131072 + 2*(size_t)E_*RPE_*4);
  int*   off       = cnt + 64;
  int*   Me        = off + 64;

  hipMemsetAsync(y, 0, (size_t)out_size*4, stream);
  hipMemsetAsync(token_src, 0, (size_t)E_*RPE_*4, stream);

  router_kernel<<<BT_, 256, 0, stream>>>(x, wr, xbf, probs2, idx2);
  scan_kernel<<<B_, 64, 0, stream>>>(idx2, pos, cnt);
  offsets_kernel<<<1, 64, 0, stream>>>(cnt, off, Me);
  fill_kernel<<<(BT_*2+255)/256, 256, 0, stream>>>(idx2, pos, off, probs2, token_src, row_prob);

  if (big){
    transp_fcg_kernel<<<dim3(H_/32, C_/32, E_), 256, 0, stream>>>(wfc, wg, wifcg);
    transp_kernel<<<dim3(C_/32, H_/32, E_), 256, 0, stream>>>(wpj, wprojT, H_, C_);
  }

  for (int e0 = 0; e0 < E_; e0 += ne){
    unsigned short* wfcg_c = wifcg;
    unsigned short* wpj_c  = wprojT;
    if (big){
      wfcg_c = wifcg  + (size_t)e0*4096*1024;
      wpj_c  = wprojT + (size_t)e0*C_*H_;
    } else {
      transp_fcg_kernel<<<dim3(H_/32, C_/32, ne), 256, 0, stream>>>(
          wfc + (size_t)e0*C_*H_, wg + (size_t)e0*C_*H_, wifcg);
      transp_kernel<<<dim3(C_/32, H_/32, ne), 256, 0, stream>>>(
          wpj + (size_t)e0*H_*C_, wprojT, H_, C_);
    }
    gemm1_kernel<<<dim3(320*ne), 512, 0, stream>>>(
        xbf, wfcg_c, token_src, Me, actc, e0);
    gemm2_kernel<<<dim3(8, 20, ne), 512, 0, stream>>>(
        actc, wpj_c, token_src, row_prob, Me, y, e0);
  }
}

// Round 16
// 741.345 us; speedup vs baseline: 1.0792x; 1.0792x over previous
//
#include <hip/hip_runtime.h>
#include <stdint.h>

#define B_   8
#define T_   2048
#define C_   1024
#define H_   2048
#define E_   8
#define CAP_ 640
#define RPE_ (B_*CAP_)   // 5120 rows per expert (max)
#define BT_  (B_*T_)     // 16384 tokens

typedef __attribute__((ext_vector_type(8))) short bf16x8;
typedef __attribute__((ext_vector_type(4))) float f32x4;

static __device__ __forceinline__ unsigned short f2bf(float f){
  union { float f; uint32_t u; } a; a.f = f;
  uint32_t u = a.u;
  uint32_t r = (u + 0x7FFFu + ((u >> 16) & 1u)) >> 16;   // RTNE
  return (unsigned short)r;
}

#define GLD16(gp, lp) __builtin_amdgcn_global_load_lds( \
    (__attribute__((address_space(1))) void*)(gp), \
    (__attribute__((address_space(3))) void*)(lp), 16, 0, 0)

#define VMW(N) asm volatile("s_waitcnt vmcnt(" #N ")" ::: "memory")
#define FENCE  asm volatile("" ::: "memory")
#define BARS   do { FENCE; __builtin_amdgcn_s_barrier(); __builtin_amdgcn_sched_barrier(0); } while(0)
#define BARE   do { __builtin_amdgcn_sched_barrier(0); FENCE; __builtin_amdgcn_s_barrier(); FENCE; } while(0)

// gemm1 register-resident fragment loads
#define LDA(H) do { \
  _Pragma("unroll") for (int ks_=0; ks_<2; ++ks_) \
  _Pragma("unroll") for (int f_=0; f_<4; ++f_) \
    pa[ks_][f_] = *(const bf16x8*)(bufc + (H)*16384u + aRow + (unsigned)f_*2048u + cc[ks_]); \
} while(0)
#define LDB(PB, H) do { \
  _Pragma("unroll") for (int ks_=0; ks_<2; ++ks_) \
  _Pragma("unroll") for (int n_=0; n_<2; ++n_) \
    PB[ks_][n_] = *(const bf16x8*)(bufc + 32768u + (H)*16384u + bRow + (unsigned)n_*2048u + cc[ks_]); \
} while(0)
#define MM16(Q, PB) do { \
  __builtin_amdgcn_s_setprio(1); \
  _Pragma("unroll") for (int ks_=0; ks_<2; ++ks_) \
  _Pragma("unroll") for (int f_=0; f_<4; ++f_) \
  _Pragma("unroll") for (int n_=0; n_<2; ++n_) \
    acc[Q][f_][n_] = __builtin_amdgcn_mfma_f32_16x16x32_bf16(pa[ks_][f_], PB[ks_][n_], acc[Q][f_][n_], 0,0,0); \
  __builtin_amdgcn_s_setprio(0); \
} while(0)

// gemm1 staging (double buffer, 64 KB stride)
#define STG_A(H, T1) do { \
  unsigned kb_ = (unsigned)(T1)*128u; \
  unsigned db_ = ((unsigned)(T1)&1u)*65536u + (H)*16384u; \
  GLD16(pA##H##0 + kb_, lds + db_ + d0); \
  GLD16(pA##H##1 + kb_, lds + db_ + 8192u + d0); \
} while(0)
#define STG_B(H, T1) do { \
  unsigned kb_ = (unsigned)(T1)*128u; \
  unsigned db_ = ((unsigned)(T1)&1u)*65536u + 32768u + (H)*16384u; \
  GLD16(pB##H##0 + kb_, lds + db_ + d0); \
  GLD16(pB##H##1 + kb_, lds + db_ + 8192u + d0); \
} while(0)

// ---------------- router: logits (fp64 acc), softmax, top-2, x->bf16 ----------------
__global__ __launch_bounds__(256) void router_kernel(
    const float* __restrict__ x, const float* __restrict__ wr,
    unsigned short* __restrict__ xbf, float* __restrict__ probs2, int* __restrict__ idx2)
{
  int bt = blockIdx.x;
  int tid = threadIdx.x;
  const float4 v = ((const float4*)(x + (size_t)bt*C_))[tid];
  ushort4 u;
  u.x = f2bf(v.x); u.y = f2bf(v.y); u.z = f2bf(v.z); u.w = f2bf(v.w);
  ((ushort4*)(xbf + (size_t)bt*C_))[tid] = u;

  double p[8];
  #pragma unroll
  for (int e=0;e<8;e++) p[e]=0.0;
  const float xv[4] = {v.x, v.y, v.z, v.w};
  #pragma unroll
  for (int j=0;j<4;j++){
    int c = tid*4+j;
    const float* wrow = wr + c*8;
    #pragma unroll
    for (int e=0;e<8;e++) p[e] += (double)xv[j] * (double)wrow[e];
  }
  __shared__ double red[8][256];
  #pragma unroll
  for (int e=0;e<8;e++) red[e][tid] = p[e];
  __syncthreads();
  for (int s=128; s>0; s>>=1){
    if (tid < s){
      #pragma unroll
      for (int e=0;e<8;e++) red[e][tid] += red[e][tid+s];
    }
    __syncthreads();
  }
  if (tid==0){
    double lg[8];
    #pragma unroll
    for (int e=0;e<8;e++) lg[e]=red[e][0];
    double mx = lg[0];
    #pragma unroll
    for (int e=1;e<8;e++) if (lg[e]>mx) mx=lg[e];
    double s=0.0, ex[8];
    #pragma unroll
    for (int e=0;e<8;e++){ ex[e]=exp(lg[e]-mx); s+=ex[e]; }
    int i1=0; double b1=ex[0];
    #pragma unroll
    for (int e=1;e<8;e++) if (ex[e]>b1){ b1=ex[e]; i1=e; }
    int i2=-1; double b2=-1.0;
    #pragma unroll
    for (int e=0;e<8;e++) if (e!=i1 && ex[e]>b2){ b2=ex[e]; i2=e; }
    probs2[bt*2+0] = (float)(b1/s);
    probs2[bt*2+1] = (float)(b2/s);
    idx2[bt*2+0] = i1;
    idx2[bt*2+1] = i2;
  }
}

// ---- fused fc+gate transpose: fp32[z][C][H] x2 -> bf16[z][4096][1024] interleaved ----
__global__ __launch_bounds__(256) void transp_fcg_kernel(
    const float* __restrict__ fc, const float* __restrict__ gate,
    unsigned short* __restrict__ dst)
{
  __shared__ float t[32][33];
  int e = blockIdx.z;
  int n0 = blockIdx.x*32, k0 = blockIdx.y*32;
  int tx = threadIdx.x & 31, ty = threadIdx.x >> 5;
  #pragma unroll
  for (int sel=0; sel<2; ++sel){
    const float* s = (sel ? gate : fc) + ((size_t)e*C_ + k0)*H_ + n0;
    #pragma unroll
    for (int i=0;i<32;i+=8) t[ty+i][tx] = s[(size_t)(ty+i)*H_ + tx];
    __syncthreads();
    #pragma unroll
    for (int i=0;i<32;i+=8){
      int jj = ty+i;
      int drow = n0*2 + ((jj & 16) << 1) + sel*16 + (jj & 15);
      dst[((size_t)e*4096 + drow)*1024 + k0 + tx] = f2bf(t[tx][jj]);
    }
    __syncthreads();
  }
}

// ---------------- weight transpose fp32[z][K][N] -> bf16[z][N][K] (w_c_proj) ----------------
__global__ __launch_bounds__(256) void transp_kernel(
    const float* __restrict__ src, unsigned short* __restrict__ dst, int K, int N)
{
  __shared__ float t[32][33];
  int e = blockIdx.z;
  int n0 = blockIdx.x*32, k0 = blockIdx.y*32;
  int tx = threadIdx.x & 31, ty = threadIdx.x >> 5;
  const float* s = src + ((size_t)e*K + k0)*N + n0;
  #pragma unroll
  for (int i=0;i<32;i+=8) t[ty+i][tx] = s[(size_t)(ty+i)*N + tx];
  __syncthreads();
  unsigned short* d = dst + ((size_t)e*N + n0)*K + k0;
  #pragma unroll
  for (int i=0;i<32;i+=8) d[(size_t)(ty+i)*K + tx] = f2bf(t[tx][ty+i]);
}

// ---------------- dispatch scan: exact k-major cumsum slot assignment ----------------
__global__ void scan_kernel(const int* __restrict__ idx2, int* __restrict__ pos, int* __restrict__ cnt)
{
  int b = blockIdx.x, lane = threadIdx.x;  // 64 threads
  unsigned long long below = (lane == 0) ? 0ull : (~0ull >> (64 - lane));
  int base = 0;
  for (int k=0;k<2;k++){
    for (int c0=0;c0<T_;c0+=64){
      int t = c0 + lane;
      int e = idx2[((b*T_ + t)<<1) + k];
      unsigned long long mym = 0; int addv = 0;
      #pragma unroll
      for (int ee=0; ee<8; ++ee){
        unsigned long long m = __ballot(e == ee);
        if (ee == e) mym = m;
        if (lane == ee) addv = __popcll(m);
      }
      int mybase = __shfl(base, e, 64);
      pos[((b*T_+t)<<1)+k] = mybase + __popcll(mym & below);
      base += addv;
    }
  }
  if (lane < 8) cnt[b*8 + lane] = (base < CAP_) ? base : CAP_;
}

__global__ void offsets_kernel(const int* __restrict__ cnt, int* __restrict__ off, int* __restrict__ Me)
{
  int e = threadIdx.x;
  if (e < 8){
    int s = 0;
    for (int b=0;b<8;b++){ off[e*8+b] = s; s += cnt[b*8+e]; }
    Me[e] = s;
  }
}

__global__ void fill_kernel(const int* __restrict__ idx2, const int* __restrict__ pos,
                            const int* __restrict__ off, const float* __restrict__ probs2,
                            int* __restrict__ token_src, float* __restrict__ row_prob)
{
  int a = blockIdx.x*256 + threadIdx.x;
  if (a >= BT_*2) return;
  int bt = a >> 1, k = a & 1;
  int b = bt >> 11;
  int e = idx2[bt*2+k];
  int p = pos[bt*2+k];
  if (p < CAP_){
    int r = e*RPE_ + off[e*8+b] + p;
    token_src[r] = bt;
    row_prob[r] = probs2[bt*2+k];
  }
}

// ---------------- GEMM1: 256x256x64, 8-phase, reg-resident halves; silu(g)*h ----------------
// 1-D grid, XCD-grouped: per-ez 320 blocks; nt = xcd + 8*(slot/20), mt = slot%20
__global__ __launch_bounds__(512, 2) void gemm1_kernel(
    const unsigned short* __restrict__ xbf,
    const unsigned short* __restrict__ wifcg,  // per-chunk base: [z][4096][1024]
    const int* __restrict__ token_src,
    const int* __restrict__ Me,
    unsigned short* __restrict__ act,          // chunk-local [z][RPE][H]
    int e0)
{
  const int lin = blockIdx.x;
  const int ez = lin / 320;
  const int r_ = lin % 320;
  const int xcd = r_ & 7, slot = r_ >> 3;          // slot 0..39
  const int nt = xcd + ((slot / 20) << 3);         // 0..15
  const int mt = slot % 20;                        // 0..19
  const int e = e0 + ez;
  const int M = Me[e];
  if (mt*256 >= M) return;

  __shared__ __align__(16) unsigned char lds[131072];

  const int tid = threadIdx.x;
  const int w = tid >> 6, l = tid & 63;
  const int wm = w >> 2, wn = w & 3;
  const int l15 = l & 15, g0 = l >> 4;
  const unsigned d0 = (unsigned)tid * 16u;

  const int srow0 = tid >> 3, c0 = tid & 7;
  const unsigned scb = (unsigned)((c0 ^ (srow0 & 7)) * 16);
  const unsigned char* gA = (const unsigned char*)xbf;
  const unsigned char* gB = (const unsigned char*)wifcg;
  const int abase = e*RPE_ + mt*256;
  const unsigned char* pA00 = gA + (size_t)token_src[abase +       srow0]*2048u + scb;
  const unsigned char* pA01 = gA + (size_t)token_src[abase +  64 + srow0]*2048u + scb;
  const unsigned char* pA10 = gA + (size_t)token_src[abase + 128 + srow0]*2048u + scb;
  const unsigned char* pA11 = gA + (size_t)token_src[abase + 192 + srow0]*2048u + scb;
  const size_t bbase = (size_t)(ez*4096 + nt*256 + srow0);
  const unsigned char* pB00 = gB + (bbase +   0)*2048u + scb;
  const unsigned char* pB01 = gB + (bbase +  64)*2048u + scb;
  const unsigned char* pB10 = gB + (bbase + 128)*2048u + scb;
  const unsigned char* pB11 = gB + (bbase + 192)*2048u + scb;

  const unsigned aRow = (unsigned)((wm*64 + l15) * 128);
  const unsigned bRow = (unsigned)((wn*32 + l15) * 128);
  unsigned cc[2];
  cc[0] = (unsigned)(((0*4 + g0) ^ (l15 & 7)) * 16);
  cc[1] = (unsigned)(((1*4 + g0) ^ (l15 & 7)) * 16);

  f32x4 acc[4][4][2];
  #pragma unroll
  for (int p=0;p<4;++p)
    #pragma unroll
    for (int f=0;f<4;++f)
      #pragma unroll
      for (int n=0;n<2;++n) acc[p][f][n] = (f32x4){0.f,0.f,0.f,0.f};

  bf16x8 pa[2][4], pb0[2][2], pb1[2][2];

  STG_A(0,0); STG_B(0,0); STG_B(1,0); STG_A(1,0);
  VMW(4);
  FENCE; __builtin_amdgcn_s_barrier(); FENCE;

  const int NT = 16;  // K=1024/64
  for (int t = 0; t < NT-1; ++t){
    const unsigned char* bufc = lds + (unsigned)(t&1)*65536u;
    LDA(0); LDB(pb0,0); STG_A(0,t+1); VMW(4); BARS; MM16(0,pb0); BARE;
    LDB(pb1,1);         STG_B(0,t+1); VMW(4); BARS; MM16(1,pb1); BARE;
    LDA(1);             STG_B(1,t+1);         BARS; MM16(2,pb0); BARE;
                        STG_A(1,t+1); VMW(4); BARS; MM16(3,pb1); BARE;
  }
  {
    const unsigned char* bufc = lds + (unsigned)((NT-1)&1)*65536u;
    LDA(0); LDB(pb0,0); VMW(2); BARS; MM16(0,pb0); BARE;
    LDB(pb1,1);         VMW(0); BARS; MM16(1,pb1); BARE;
    LDA(1);                     BARS; MM16(2,pb0); BARE;
                                BARS; MM16(3,pb1); BARE;
  }

  // epilogue: n=0 frag = h, n=1 frag = g (same logical cols); act = silu(g)*h
  const int r4 = (l >> 4) * 4;
  #pragma unroll
  for (int p=0;p<4;++p){
    const int ah = p>>1, bh = p&1;
    #pragma unroll
    for (int f=0;f<4;++f){
      const int grow = mt*256 + ah*128 + wm*64 + f*16 + r4;
      const int hcol = nt*128 + bh*64 + wn*16 + l15;
      #pragma unroll
      for (int r=0;r<4;++r){
        float h = acc[p][f][0][r];
        float gv = acc[p][f][1][r];
        float a = (gv / (1.f + __expf(-gv))) * h;
        act[((size_t)ez*RPE_ + grow + r)*(size_t)H_ + hcol] = f2bf(a);
      }
    }
  }
}

// ---- GEMM2: 128x128x64, 2-phase dbuf 64KB, 256 thr (2 blk/CU); atomic scatter ----
// flat grid: per-ez 320 blocks; xcd=r&7, slot=r>>3; mt=xcd+8*(slot>>3) (0..39), nt=slot&7
__global__ __launch_bounds__(256) void gemm2_kernel(
    const unsigned short* __restrict__ act,     // chunk-local [z][RPE][H]
    const unsigned short* __restrict__ wprojT,  // per-chunk base: [z][C][H]
    const int* __restrict__ token_src,
    const float* __restrict__ row_prob,
    const int* __restrict__ Me,
    float* __restrict__ y,
    int e0)
{
  const int lin = blockIdx.x;
  const int ez = lin / 320;
  const int r_ = lin % 320;
  const int xcd = r_ & 7, slot = r_ >> 3;      // slot 0..39
  const int mt = xcd + ((slot >> 3) << 3);     // 0..39
  const int nt = slot & 7;                     // 0..7
  const int e = e0 + ez;
  const int M = Me[e];
  if (mt*128 >= M) return;

  __shared__ __align__(16) unsigned char lds[2][32768];   // [buf][A 16K | B 16K]

  const int tid = threadIdx.x;
  const int w = tid >> 6, l = tid & 63;
  const int wrow = w >> 1, wcol = w & 1;
  const int r8 = l >> 3;
  const unsigned swz16 = (unsigned)(((l & 7) ^ r8) * 16);

  unsigned ldsOff[4];
  size_t offA[4], offB[4];
  #pragma unroll
  for (int j = 0; j < 4; ++j){
    int row = w*32 + j*8 + r8;
    offA[j] = ((size_t)(ez*RPE_ + mt*128 + row))*4096u + swz16;
    offB[j] = ((size_t)(ez*C_   + nt*128 + row))*4096u + swz16;
    ldsOff[j] = (unsigned)(w*32 + j*8) * 128u;
  }

  f32x4 acc[4][4];
  #pragma unroll
  for (int i=0;i<4;i++)
    #pragma unroll
    for (int j=0;j<4;j++) acc[i][j] = (f32x4){0.f,0.f,0.f,0.f};

  const unsigned char* gA = (const unsigned char*)act;
  const unsigned char* gB = (const unsigned char*)wprojT;

  auto stage = [&](int kt, int bb){
    const unsigned kb = (unsigned)kt * 128u;
    #pragma unroll
    for (int j=0;j<4;++j) GLD16(gA + offA[j] + kb, &lds[bb][0]     + ldsOff[j]);
    #pragma unroll
    for (int j=0;j<4;++j) GLD16(gB + offB[j] + kb, &lds[bb][16384] + ldsOff[j]);
  };
  auto compute = [&](int bb){
    #pragma unroll
    for (int kh=0; kh<2; ++kh){
      bf16x8 afr[4], bfr[4];
      #pragma unroll
      for (int fm=0; fm<4; ++fm){
        int row = wrow*64 + fm*16 + (l & 15);
        int gnum = kh*4 + (l >> 4);
        int byt = row*128 + ((gnum ^ (row & 7)) * 16);
        afr[fm] = *(const bf16x8*)(&lds[bb][0] + byt);
      }
      #pragma unroll
      for (int fn=0; fn<4; ++fn){
        int row = wcol*64 + fn*16 + (l & 15);
        int gnum = kh*4 + (l >> 4);
        int byt = row*128 + ((gnum ^ (row & 7)) * 16);
        bfr[fn] = *(const bf16x8*)(&lds[bb][16384] + byt);
      }
      #pragma unroll
      for (int fm=0; fm<4; ++fm)
        #pragma unroll
        for (int fn=0; fn<4; ++fn)
          acc[fm][fn] = __builtin_amdgcn_mfma_f32_16x16x32_bf16(afr[fm], bfr[fn], acc[fm][fn], 0,0,0);
    }
  };

  stage(0, 0);
  __syncthreads();
  const int NT = 32;  // K=2048/64
  for (int kt = 0; kt < NT; ++kt){
    if (kt+1 < NT) stage(kt+1, (kt+1)&1);
    compute(kt&1);
    __syncthreads();
  }

  // epilogue: scatter p * o into y (atomic, <=2 contributions per y element)
  #pragma unroll
  for (int fm=0; fm<4; ++fm){
    #pragma unroll
    for (int r=0; r<4; ++r){
      int rloc = mt*128 + wrow*64 + fm*16 + (l>>4)*4 + r;
      if (rloc < M){
        int bt  = token_src[e*RPE_ + rloc];
        float p = row_prob[e*RPE_ + rloc];
        float* yrow = y + (size_t)bt*C_;
        #pragma unroll
        for (int fn=0; fn<4; ++fn){
          int col = nt*128 + wcol*64 + fn*16 + (l & 15);
          atomicAdd(yrow + col, p * acc[fm][fn][r]);
        }
      }
    }
  }
}

extern "C" void kernel_launch(void* const* d_in, const int* in_sizes, int n_in,
                              void* d_out, int out_size, void* d_ws, size_t ws_size,
                              hipStream_t stream)
{
  const float* x   = (const float*)d_in[0];
  const float* wr  = (const float*)d_in[1];
  const float* wfc = (const float*)d_in[2];
  const float* wg  = (const float*)d_in[3];
  const float* wpj = (const float*)d_in[4];
  float* y = (float*)d_out;

  unsigned char* ws = (unsigned char*)d_ws;
  const size_t szXBF  = (size_t)BT_*C_*2;            // 33,554,432
  const size_t szFCGc = (size_t)2*4096*1024*2;       // 16,777,216
  const size_t szWPc  = (size_t)2*C_*H_*2;           //  8,388,608
  const size_t szFCGa = (size_t)E_*4096*1024*2;      // 67,108,864
  const size_t szWPa  = (size_t)E_*C_*H_*2;          // 33,554,432
  const size_t szMISC = 3*131072 + 2*(size_t)E_*RPE_*4 + 1024;

  const size_t need_small = szXBF + szFCGc + szWPc + (size_t)2*RPE_*H_*2 + szMISC;
  const size_t need_big2  = szXBF + szFCGa + szWPa  + (size_t)2*RPE_*H_*2 + szMISC;
  const size_t need_big4  = szXBF + szFCGa + szWPa  + (size_t)4*RPE_*H_*2 + szMISC;
  if (ws_size < need_small) return;
  const bool big4 = (ws_size >= need_big4);
  const bool big  = big4 || (ws_size >= need_big2);
  const int  ne   = big4 ? 4 : 2;

  const size_t szFCG = big ? szFCGa : szFCGc;
  const size_t szWP  = big ? szWPa  : szWPc;
  const size_t szACT = (size_t)ne*RPE_*H_*2;

  size_t oXBF = 0;
  size_t oFCG = oXBF + szXBF;
  size_t oWP  = oFCG + szFCG;
  size_t oACT = oWP  + szWP;
  size_t oM   = oACT + szACT;

  unsigned short* xbf    = (unsigned short*)(ws + oXBF);
  unsigned short* wifcg  = (unsigned short*)(ws + oFCG);
  unsigned short* wprojT = (unsigned short*)(ws + oWP);
  unsigned short* actc   = (unsigned short*)(ws + oACT);

  float* probs2    = (float*)(ws + oM);
  int*   idx2      = (int*)(ws + oM + 1*131072);
  int*   pos       = (int*)(ws + oM + 2*131072);
  int*   token_src = (int*)(ws + oM + 3*131072);
  float* row_prob  = (float*)(ws + oM + 3*131072 + (size_t)E_*RPE_*4);
  int*   cnt       = (int*)(ws + oM + 3*131072 + 2*(size_t)E_*RPE_*4);
  int*   off       = cnt + 64;
  int*   Me        = off + 64;

  hipMemsetAsync(y, 0, (size_t)out_size*4, stream);
  hipMemsetAsync(token_src, 0, (size_t)E_*RPE_*4, stream);

  router_kernel<<<BT_, 256, 0, stream>>>(x, wr, xbf, probs2, idx2);
  scan_kernel<<<B_, 64, 0, stream>>>(idx2, pos, cnt);
  offsets_kernel<<<1, 64, 0, stream>>>(cnt, off, Me);
  fill_kernel<<<(BT_*2+255)/256, 256, 0, stream>>>(idx2, pos, off, probs2, token_src, row_prob);

  if (big){
    transp_fcg_kernel<<<dim3(H_/32, C_/32, E_), 256, 0, stream>>>(wfc, wg, wifcg);
    transp_kernel<<<dim3(C_/32, H_/32, E_), 256, 0, stream>>>(wpj, wprojT, H_, C_);
  }

  for (int e0 = 0; e0 < E_; e0 += ne){
    unsigned short* wfcg_c = wifcg;
    unsigned short* wpj_c  = wprojT;
    if (big){
      wfcg_c = wifcg  + (size_t)e0*4096*1024;
      wpj_c  = wprojT + (size_t)e0*C_*H_;
    } else {
      transp_fcg_kernel<<<dim3(H_/32, C_/32, ne), 256, 0, stream>>>(
          wfc + (size_t)e0*C_*H_, wg + (size_t)e0*C_*H_, wifcg);
      transp_kernel<<<dim3(C_/32, H_/32, ne), 256, 0, stream>>>(
          wpj + (size_t)e0*H_*C_, wprojT, H_, C_);
    }
    gemm1_kernel<<<dim3(320*ne), 512, 0, stream>>>(
        xbf, wfcg_c, token_src, Me, actc, e0);
    gemm2_kernel<<<dim3(320*ne), 256, 0, stream>>>(
        actc, wpj_c, token_src, row_prob, Me, y, e0);
  }
}

// Round 17
// 735.126 us; speedup vs baseline: 1.0883x; 1.0085x over previous
//
#include <hip/hip_runtime.h>
#include <stdint.h>

#define B_   8
#define T_   2048
#define C_   1024
#define H_   2048
#define E_   8
#define CAP_ 640
#define RPE_ (B_*CAP_)   // 5120 rows per expert (max)
#define BT_  (B_*T_)     // 16384 tokens

typedef __attribute__((ext_vector_type(8))) short bf16x8;
typedef __attribute__((ext_vector_type(4))) float f32x4;

static __device__ __forceinline__ unsigned short f2bf(float f){
  union { float f; uint32_t u; } a; a.f = f;
  uint32_t u = a.u;
  uint32_t r = (u + 0x7FFFu + ((u >> 16) & 1u)) >> 16;   // RTNE
  return (unsigned short)r;
}

#define GLD16(gp, lp) __builtin_amdgcn_global_load_lds( \
    (__attribute__((address_space(1))) void*)(gp), \
    (__attribute__((address_space(3))) void*)(lp), 16, 0, 0)

#define VMW(N) asm volatile("s_waitcnt vmcnt(" #N ")" ::: "memory")
#define FENCE  asm volatile("" ::: "memory")
#define BARS   do { FENCE; __builtin_amdgcn_s_barrier(); __builtin_amdgcn_sched_barrier(0); } while(0)
#define BARE   do { __builtin_amdgcn_sched_barrier(0); FENCE; __builtin_amdgcn_s_barrier(); FENCE; } while(0)

// gemm1 register-resident fragment loads
#define LDA(H) do { \
  _Pragma("unroll") for (int ks_=0; ks_<2; ++ks_) \
  _Pragma("unroll") for (int f_=0; f_<4; ++f_) \
    pa[ks_][f_] = *(const bf16x8*)(bufc + (H)*16384u + aRow + (unsigned)f_*2048u + cc[ks_]); \
} while(0)
#define LDB(PB, H) do { \
  _Pragma("unroll") for (int ks_=0; ks_<2; ++ks_) \
  _Pragma("unroll") for (int n_=0; n_<2; ++n_) \
    PB[ks_][n_] = *(const bf16x8*)(bufc + 32768u + (H)*16384u + bRow + (unsigned)n_*2048u + cc[ks_]); \
} while(0)
#define MM16(Q, PB) do { \
  __builtin_amdgcn_s_setprio(1); \
  _Pragma("unroll") for (int ks_=0; ks_<2; ++ks_) \
  _Pragma("unroll") for (int f_=0; f_<4; ++f_) \
  _Pragma("unroll") for (int n_=0; n_<2; ++n_) \
    acc[Q][f_][n_] = __builtin_amdgcn_mfma_f32_16x16x32_bf16(pa[ks_][f_], PB[ks_][n_], acc[Q][f_][n_], 0,0,0); \
  __builtin_amdgcn_s_setprio(0); \
} while(0)

// gemm1 staging (double buffer, 64 KB stride)
#define STG_A(H, T1) do { \
  unsigned kb_ = (unsigned)(T1)*128u; \
  unsigned db_ = ((unsigned)(T1)&1u)*65536u + (H)*16384u; \
  GLD16(pA##H##0 + kb_, lds + db_ + d0); \
  GLD16(pA##H##1 + kb_, lds + db_ + 8192u + d0); \
} while(0)
#define STG_B(H, T1) do { \
  unsigned kb_ = (unsigned)(T1)*128u; \
  unsigned db_ = ((unsigned)(T1)&1u)*65536u + 32768u + (H)*16384u; \
  GLD16(pB##H##0 + kb_, lds + db_ + d0); \
  GLD16(pB##H##1 + kb_, lds + db_ + 8192u + d0); \
} while(0)

// ---------------- router: logits (fp64 acc), softmax, top-2, x->bf16, zero y ----------------
__global__ __launch_bounds__(256) void router_kernel(
    const float* __restrict__ x, const float* __restrict__ wr,
    unsigned short* __restrict__ xbf, float* __restrict__ probs2, int* __restrict__ idx2,
    float* __restrict__ y)
{
  int bt = blockIdx.x;
  int tid = threadIdx.x;
  const float4 v = ((const float4*)(x + (size_t)bt*C_))[tid];
  ushort4 u;
  u.x = f2bf(v.x); u.y = f2bf(v.y); u.z = f2bf(v.z); u.w = f2bf(v.w);
  ((ushort4*)(xbf + (size_t)bt*C_))[tid] = u;
  // zero this token's y row (replaces global memset; runs before gemm2 atomics)
  ((float4*)(y + (size_t)bt*C_))[tid] = (float4){0.f,0.f,0.f,0.f};

  double p[8];
  #pragma unroll
  for (int e=0;e<8;e++) p[e]=0.0;
  const float xv[4] = {v.x, v.y, v.z, v.w};
  #pragma unroll
  for (int j=0;j<4;j++){
    int c = tid*4+j;
    const float* wrow = wr + c*8;
    #pragma unroll
    for (int e=0;e<8;e++) p[e] += (double)xv[j] * (double)wrow[e];
  }
  __shared__ double red[8][256];
  #pragma unroll
  for (int e=0;e<8;e++) red[e][tid] = p[e];
  __syncthreads();
  for (int s=128; s>0; s>>=1){
    if (tid < s){
      #pragma unroll
      for (int e=0;e<8;e++) red[e][tid] += red[e][tid+s];
    }
    __syncthreads();
  }
  if (tid==0){
    double lg[8];
    #pragma unroll
    for (int e=0;e<8;e++) lg[e]=red[e][0];
    double mx = lg[0];
    #pragma unroll
    for (int e=1;e<8;e++) if (lg[e]>mx) mx=lg[e];
    double s=0.0, ex[8];
    #pragma unroll
    for (int e=0;e<8;e++){ ex[e]=exp(lg[e]-mx); s+=ex[e]; }
    int i1=0; double b1=ex[0];
    #pragma unroll
    for (int e=1;e<8;e++) if (ex[e]>b1){ b1=ex[e]; i1=e; }
    int i2=-1; double b2=-1.0;
    #pragma unroll
    for (int e=0;e<8;e++) if (e!=i1 && ex[e]>b2){ b2=ex[e]; i2=e; }
    probs2[bt*2+0] = (float)(b1/s);
    probs2[bt*2+1] = (float)(b2/s);
    idx2[bt*2+0] = i1;
    idx2[bt*2+1] = i2;
  }
}

// ---- fused fc+gate transpose: fp32[z][C][H] x2 -> bf16[z][4096][1024] interleaved ----
__global__ __launch_bounds__(256) void transp_fcg_kernel(
    const float* __restrict__ fc, const float* __restrict__ gate,
    unsigned short* __restrict__ dst)
{
  __shared__ float t[32][33];
  int e = blockIdx.z;
  int n0 = blockIdx.x*32, k0 = blockIdx.y*32;
  int tx = threadIdx.x & 31, ty = threadIdx.x >> 5;
  #pragma unroll
  for (int sel=0; sel<2; ++sel){
    const float* s = (sel ? gate : fc) + ((size_t)e*C_ + k0)*H_ + n0;
    #pragma unroll
    for (int i=0;i<32;i+=8) t[ty+i][tx] = s[(size_t)(ty+i)*H_ + tx];
    __syncthreads();
    #pragma unroll
    for (int i=0;i<32;i+=8){
      int jj = ty+i;
      int drow = n0*2 + ((jj & 16) << 1) + sel*16 + (jj & 15);
      dst[((size_t)e*4096 + drow)*1024 + k0 + tx] = f2bf(t[tx][jj]);
    }
    __syncthreads();
  }
}

// ---------------- weight transpose fp32[z][K][N] -> bf16[z][N][K] (w_c_proj) ----------------
__global__ __launch_bounds__(256) void transp_kernel(
    const float* __restrict__ src, unsigned short* __restrict__ dst, int K, int N)
{
  __shared__ float t[32][33];
  int e = blockIdx.z;
  int n0 = blockIdx.x*32, k0 = blockIdx.y*32;
  int tx = threadIdx.x & 31, ty = threadIdx.x >> 5;
  const float* s = src + ((size_t)e*K + k0)*N + n0;
  #pragma unroll
  for (int i=0;i<32;i+=8) t[ty+i][tx] = s[(size_t)(ty+i)*N + tx];
  __syncthreads();
  unsigned short* d = dst + ((size_t)e*N + n0)*K + k0;
  #pragma unroll
  for (int i=0;i<32;i+=8) d[(size_t)(ty+i)*K + tx] = f2bf(t[tx][ty+i]);
}

// ---------------- dispatch scan: exact k-major cumsum slot assignment ----------------
__global__ void scan_kernel(const int* __restrict__ idx2, int* __restrict__ pos, int* __restrict__ cnt)
{
  int b = blockIdx.x, lane = threadIdx.x;  // 64 threads
  unsigned long long below = (lane == 0) ? 0ull : (~0ull >> (64 - lane));
  int base = 0;
  for (int k=0;k<2;k++){
    for (int c0=0;c0<T_;c0+=64){
      int t = c0 + lane;
      int e = idx2[((b*T_ + t)<<1) + k];
      unsigned long long mym = 0; int addv = 0;
      #pragma unroll
      for (int ee=0; ee<8; ++ee){
        unsigned long long m = __ballot(e == ee);
        if (ee == e) mym = m;
        if (lane == ee) addv = __popcll(m);
      }
      int mybase = __shfl(base, e, 64);
      pos[((b*T_+t)<<1)+k] = mybase + __popcll(mym & below);
      base += addv;
    }
  }
  if (lane < 8) cnt[b*8 + lane] = (base < CAP_) ? base : CAP_;
}

__global__ void offsets_kernel(const int* __restrict__ cnt, int* __restrict__ off, int* __restrict__ Me)
{
  int e = threadIdx.x;
  if (e < 8){
    int s = 0;
    for (int b=0;b<8;b++){ off[e*8+b] = s; s += cnt[b*8+e]; }
    Me[e] = s;
  }
}

__global__ void fill_kernel(const int* __restrict__ idx2, const int* __restrict__ pos,
                            const int* __restrict__ off, const float* __restrict__ probs2,
                            int* __restrict__ token_src, float* __restrict__ row_prob)
{
  int a = blockIdx.x*256 + threadIdx.x;
  if (a >= BT_*2) return;
  int bt = a >> 1, k = a & 1;
  int b = bt >> 11;
  int e = idx2[bt*2+k];
  int p = pos[bt*2+k];
  if (p < CAP_){
    int r = e*RPE_ + off[e*8+b] + p;
    token_src[r] = bt;
    row_prob[r] = probs2[bt*2+k];
  }
}

// ---------------- GEMM1: 256x256x64, 8-phase, reg-resident halves; silu(g)*h ----------------
// 1-D grid, XCD-grouped: per-ez 320 blocks; nt = xcd + 8*(slot/20), mt = slot%20
__global__ __launch_bounds__(512, 2) void gemm1_kernel(
    const unsigned short* __restrict__ xbf,
    const unsigned short* __restrict__ wifcg,  // per-chunk base: [z][4096][1024]
    const int* __restrict__ token_src,
    const int* __restrict__ Me,
    unsigned short* __restrict__ act,          // chunk-local [z][RPE][H]
    int e0)
{
  const int lin = blockIdx.x;
  const int ez = lin / 320;
  const int r_ = lin % 320;
  const int xcd = r_ & 7, slot = r_ >> 3;          // slot 0..39
  const int nt = xcd + ((slot / 20) << 3);         // 0..15
  const int mt = slot % 20;                        // 0..19
  const int e = e0 + ez;
  const int M = Me[e];
  if (mt*256 >= M) return;

  __shared__ __align__(16) unsigned char lds[131072];

  const int tid = threadIdx.x;
  const int w = tid >> 6, l = tid & 63;
  const int wm = w >> 2, wn = w & 3;
  const int l15 = l & 15, g0 = l >> 4;
  const unsigned d0 = (unsigned)tid * 16u;

  const int srow0 = tid >> 3, c0 = tid & 7;
  const unsigned scb = (unsigned)((c0 ^ (srow0 & 7)) * 16);
  const unsigned char* gA = (const unsigned char*)xbf;
  const unsigned char* gB = (const unsigned char*)wifcg;
  const int abase = e*RPE_ + mt*256;
  const unsigned char* pA00 = gA + (size_t)token_src[abase +       srow0]*2048u + scb;
  const unsigned char* pA01 = gA + (size_t)token_src[abase +  64 + srow0]*2048u + scb;
  const unsigned char* pA10 = gA + (size_t)token_src[abase + 128 + srow0]*2048u + scb;
  const unsigned char* pA11 = gA + (size_t)token_src[abase + 192 + srow0]*2048u + scb;
  const size_t bbase = (size_t)(ez*4096 + nt*256 + srow0);
  const unsigned char* pB00 = gB + (bbase +   0)*2048u + scb;
  const unsigned char* pB01 = gB + (bbase +  64)*2048u + scb;
  const unsigned char* pB10 = gB + (bbase + 128)*2048u + scb;
  const unsigned char* pB11 = gB + (bbase + 192)*2048u + scb;

  const unsigned aRow = (unsigned)((wm*64 + l15) * 128);
  const unsigned bRow = (unsigned)((wn*32 + l15) * 128);
  unsigned cc[2];
  cc[0] = (unsigned)(((0*4 + g0) ^ (l15 & 7)) * 16);
  cc[1] = (unsigned)(((1*4 + g0) ^ (l15 & 7)) * 16);

  f32x4 acc[4][4][2];
  #pragma unroll
  for (int p=0;p<4;++p)
    #pragma unroll
    for (int f=0;f<4;++f)
      #pragma unroll
      for (int n=0;n<2;++n) acc[p][f][n] = (f32x4){0.f,0.f,0.f,0.f};

  bf16x8 pa[2][4], pb0[2][2], pb1[2][2];

  STG_A(0,0); STG_B(0,0); STG_B(1,0); STG_A(1,0);
  VMW(4);
  FENCE; __builtin_amdgcn_s_barrier(); FENCE;

  const int NT = 16;  // K=1024/64
  for (int t = 0; t < NT-1; ++t){
    const unsigned char* bufc = lds + (unsigned)(t&1)*65536u;
    LDA(0); LDB(pb0,0); STG_A(0,t+1); VMW(4); BARS; MM16(0,pb0); BARE;
    LDB(pb1,1);         STG_B(0,t+1); VMW(4); BARS; MM16(1,pb1); BARE;
    LDA(1);             STG_B(1,t+1);         BARS; MM16(2,pb0); BARE;
                        STG_A(1,t+1); VMW(4); BARS; MM16(3,pb1); BARE;
  }
  {
    const unsigned char* bufc = lds + (unsigned)((NT-1)&1)*65536u;
    LDA(0); LDB(pb0,0); VMW(2); BARS; MM16(0,pb0); BARE;
    LDB(pb1,1);         VMW(0); BARS; MM16(1,pb1); BARE;
    LDA(1);                     BARS; MM16(2,pb0); BARE;
                                BARS; MM16(3,pb1); BARE;
  }

  // epilogue: n=0 frag = h, n=1 frag = g (same logical cols); act = silu(g)*h
  const int r4 = (l >> 4) * 4;
  #pragma unroll
  for (int p=0;p<4;++p){
    const int ah = p>>1, bh = p&1;
    #pragma unroll
    for (int f=0;f<4;++f){
      const int grow = mt*256 + ah*128 + wm*64 + f*16 + r4;
      const int hcol = nt*128 + bh*64 + wn*16 + l15;
      #pragma unroll
      for (int r=0;r<4;++r){
        float h = acc[p][f][0][r];
        float gv = acc[p][f][1][r];
        float a = (gv / (1.f + __expf(-gv))) * h;
        act[((size_t)ez*RPE_ + grow + r)*(size_t)H_ + hcol] = f2bf(a);
      }
    }
  }
}

// ---- GEMM2: 128x128x64, 2-phase dbuf 64KB, 256 thr (2 blk/CU); atomic scatter ----
// flat grid: per-ez 320 blocks; xcd=r&7, slot=r>>3; mt=xcd+8*(slot>>3) (0..39), nt=slot&7
__global__ __launch_bounds__(256) void gemm2_kernel(
    const unsigned short* __restrict__ act,     // chunk-local [z][RPE][H]
    const unsigned short* __restrict__ wprojT,  // per-chunk base: [z][C][H]
    const int* __restrict__ token_src,
    const float* __restrict__ row_prob,
    const int* __restrict__ Me,
    float* __restrict__ y,
    int e0)
{
  const int lin = blockIdx.x;
  const int ez = lin / 320;
  const int r_ = lin % 320;
  const int xcd = r_ & 7, slot = r_ >> 3;      // slot 0..39
  const int mt = xcd + ((slot >> 3) << 3);     // 0..39
  const int nt = slot & 7;                     // 0..7
  const int e = e0 + ez;
  const int M = Me[e];
  if (mt*128 >= M) return;

  __shared__ __align__(16) unsigned char lds[2][32768];   // [buf][A 16K | B 16K]

  const int tid = threadIdx.x;
  const int w = tid >> 6, l = tid & 63;
  const int wrow = w >> 1, wcol = w & 1;
  const int r8 = l >> 3;
  const unsigned swz16 = (unsigned)(((l & 7) ^ r8) * 16);

  unsigned ldsOff[4];
  size_t offA[4], offB[4];
  #pragma unroll
  for (int j = 0; j < 4; ++j){
    int row = w*32 + j*8 + r8;
    offA[j] = ((size_t)(ez*RPE_ + mt*128 + row))*4096u + swz16;
    offB[j] = ((size_t)(ez*C_   + nt*128 + row))*4096u + swz16;
    ldsOff[j] = (unsigned)(w*32 + j*8) * 128u;
  }

  f32x4 acc[4][4];
  #pragma unroll
  for (int i=0;i<4;i++)
    #pragma unroll
    for (int j=0;j<4;j++) acc[i][j] = (f32x4){0.f,0.f,0.f,0.f};

  const unsigned char* gA = (const unsigned char*)act;
  const unsigned char* gB = (const unsigned char*)wprojT;

  auto stage = [&](int kt, int bb){
    const unsigned kb = (unsigned)kt * 128u;
    #pragma unroll
    for (int j=0;j<4;++j) GLD16(gA + offA[j] + kb, &lds[bb][0]     + ldsOff[j]);
    #pragma unroll
    for (int j=0;j<4;++j) GLD16(gB + offB[j] + kb, &lds[bb][16384] + ldsOff[j]);
  };
  auto compute = [&](int bb){
    #pragma unroll
    for (int kh=0; kh<2; ++kh){
      bf16x8 afr[4], bfr[4];
      #pragma unroll
      for (int fm=0; fm<4; ++fm){
        int row = wrow*64 + fm*16 + (l & 15);
        int gnum = kh*4 + (l >> 4);
        int byt = row*128 + ((gnum ^ (row & 7)) * 16);
        afr[fm] = *(const bf16x8*)(&lds[bb][0] + byt);
      }
      #pragma unroll
      for (int fn=0; fn<4; ++fn){
        int row = wcol*64 + fn*16 + (l & 15);
        int gnum = kh*4 + (l >> 4);
        int byt = row*128 + ((gnum ^ (row & 7)) * 16);
        bfr[fn] = *(const bf16x8*)(&lds[bb][16384] + byt);
      }
      #pragma unroll
      for (int fm=0; fm<4; ++fm)
        #pragma unroll
        for (int fn=0; fn<4; ++fn)
          acc[fm][fn] = __builtin_amdgcn_mfma_f32_16x16x32_bf16(afr[fm], bfr[fn], acc[fm][fn], 0,0,0);
    }
  };

  stage(0, 0);
  __syncthreads();
  const int NT = 32;  // K=2048/64
  for (int kt = 0; kt < NT; ++kt){
    if (kt+1 < NT) stage(kt+1, (kt+1)&1);
    compute(kt&1);
    __syncthreads();
  }

  // epilogue: scatter p * o into y (atomic, <=2 contributions per y element)
  #pragma unroll
  for (int fm=0; fm<4; ++fm){
    #pragma unroll
    for (int r=0; r<4; ++r){
      int rloc = mt*128 + wrow*64 + fm*16 + (l>>4)*4 + r;
      if (rloc < M){
        int bt  = token_src[e*RPE_ + rloc];
        float p = row_prob[e*RPE_ + rloc];
        float* yrow = y + (size_t)bt*C_;
        #pragma unroll
        for (int fn=0; fn<4; ++fn){
          int col = nt*128 + wcol*64 + fn*16 + (l & 15);
          atomicAdd(yrow + col, p * acc[fm][fn][r]);
        }
      }
    }
  }
}

extern "C" void kernel_launch(void* const* d_in, const int* in_sizes, int n_in,
                              void* d_out, int out_size, void* d_ws, size_t ws_size,
                              hipStream_t stream)
{
  const float* x   = (const float*)d_in[0];
  const float* wr  = (const float*)d_in[1];
  const float* wfc = (const float*)d_in[2];
  const float* wg  = (const float*)d_in[3];
  const float* wpj = (const float*)d_in[4];
  float* y = (float*)d_out;

  unsigned char* ws = (unsigned char*)d_ws;
  const size_t szXBF  = (size_t)BT_*C_*2;            // 33,554,432
  const size_t szFCGc = (size_t)2*4096*1024*2;       // 16,777,216
  const size_t szWPc  = (size_t)2*C_*H_*2;           //  8,388,608
  const size_t szFCGa = (size_t)E_*4096*1024*2;      // 67,108,864
  const size_t szWPa  = (size_t)E_*C_*H_*2;          // 33,554,432
  const size_t szMISC = 3*131072 + 2*(size_t)E_*RPE_*4 + 1024;

  const size_t need_small = szXBF + szFCGc + szWPc + (size_t)2*RPE_*H_*2 + szMISC;
  const size_t need_big2  = szXBF + szFCGa + szWPa  + (size_t)2*RPE_*H_*2 + szMISC;
  const size_t need_big4  = szXBF + szFCGa + szWPa  + (size_t)4*RPE_*H_*2 + szMISC;
  if (ws_size < need_small) return;
  const bool big4 = (ws_size >= need_big4);
  const bool big  = big4 || (ws_size >= need_big2);
  const int  ne   = big4 ? 4 : 2;

  const size_t szFCG = big ? szFCGa : szFCGc;
  const size_t szWP  = big ? szWPa  : szWPc;
  const size_t szACT = (size_t)ne*RPE_*H_*2;

  size_t oXBF = 0;
  size_t oFCG = oXBF + szXBF;
  size_t oWP  = oFCG + szFCG;
  size_t oACT = oWP  + szWP;
  size_t oM   = oACT + szACT;

  unsigned short* xbf    = (unsigned short*)(ws + oXBF);
  unsigned short* wifcg  = (unsigned short*)(ws + oFCG);
  unsigned short* wprojT = (unsigned short*)(ws + oWP);
  unsigned short* actc   = (unsigned short*)(ws + oACT);

  float* probs2    = (float*)(ws + oM);
  int*   idx2      = (int*)(ws + oM + 1*131072);
  int*   pos       = (int*)(ws + oM + 2*131072);
  int*   token_src = (int*)(ws + oM + 3*131072);
  float* row_prob  = (float*)(ws + oM + 3*131072 + (size_t)E_*RPE_*4);
  int*   cnt       = (int*)(ws + oM + 3*131072 + 2*(size_t)E_*RPE_*4);
  int*   off       = cnt + 64;
  int*   Me        = off + 64;

  hipMemsetAsync(token_src, 0, (size_t)E_*RPE_*4, stream);

  router_kernel<<<BT_, 256, 0, stream>>>(x, wr, xbf, probs2, idx2, y);
  scan_kernel<<<B_, 64, 0, stream>>>(idx2, pos, cnt);
  offsets_kernel<<<1, 64, 0, stream>>>(cnt, off, Me);
  fill_kernel<<<(BT_*2+255)/256, 256, 0, stream>>>(idx2, pos, off, probs2, token_src, row_prob);

  if (big){
    transp_fcg_kernel<<<dim3(H_/32, C_/32, E_), 256, 0, stream>>>(wfc, wg, wifcg);
    transp_kernel<<<dim3(C_/32, H_/32, E_), 256, 0, stream>>>(wpj, wprojT, H_, C_);
  }

  for (int e0 = 0; e0 < E_; e0 += ne){
    unsigned short* wfcg_c = wifcg;
    unsigned short* wpj_c  = wprojT;
    if (big){
      wfcg_c = wifcg  + (size_t)e0*4096*1024;
      wpj_c  = wprojT + (size_t)e0*C_*H_;
    } else {
      transp_fcg_kernel<<<dim3(H_/32, C_/32, ne), 256, 0, stream>>>(
          wfc + (size_t)e0*C_*H_, wg + (size_t)e0*C_*H_, wifcg);
      transp_kernel<<<dim3(C_/32, H_/32, ne), 256, 0, stream>>>(
          wpj + (size_t)e0*H_*C_, wprojT, H_, C_);
    }
    gemm1_kernel<<<dim3(320*ne), 512, 0, stream>>>(
        xbf, wfcg_c, token_src, Me, actc, e0);
    gemm2_kernel<<<dim3(320*ne), 256, 0, stream>>>(
        actc, wpj_c, token_src, row_prob, Me, y, e0);
  }
}